// Round 14
// baseline (144.439 us; speedup 1.0000x reference)
//
#include <hip/hip_runtime.h>

typedef float f32x4 __attribute__((ext_vector_type(4)));
typedef unsigned long long ull;

#define OFF_PRED 26214400      // 32*128*128*50
#define OFF_XU   56934400      // OFF_PRED + 32*64*300*50
#define NBP 8                  // bp per persistent block; grid = 2048/8 = 256 = 1/CU
#define LROW 328               // LDS row stride in bytes (fp8): 320 + 8 pad -> 16-bank spread

// pack 4 floats into 4 fp8 e4m3 bytes (one u32)
__device__ inline unsigned pack4_fp8(float a, float b, float c, float d) {
    int r = __builtin_amdgcn_cvt_pk_fp8_f32(a, b, 0, false);   // bytes 0,1
    r = __builtin_amdgcn_cvt_pk_fp8_f32(c, d, r, true);        // bytes 2,3
    return (unsigned)r;
}

// ---- K0: build M in MFMA-fragment order, fp8.
// Logical M[640][320]: rows 0..255 = C, 256..555 = A, rest 0; cols k<300 real, else 0.
// frag elem byte = ((mt*10+ks)*64 + lane)*8 + e ; m = mt*16 + (lane&15), k = ks*32 + (lane>>4)*8 + e.
__global__ void build_M(const float* __restrict__ A, const float* __restrict__ C,
                        unsigned* __restrict__ M) {
    int idx = blockIdx.x * 256 + threadIdx.x;      // u32 index (4 fp8 elems)
    if (idx >= 51200) return;                      // 640*320/4
    int d = idx * 4;
    int e0 = d & 7, lane = (d >> 3) & 63, fs = d >> 9;
    int mt = fs / 10, ks = fs % 10;
    int m = mt * 16 + (lane & 15);
    int k = ks * 32 + (lane >> 4) * 8 + e0;
    float f0 = 0.f, f1 = 0.f, f2 = 0.f, f3 = 0.f;
    const float* src = nullptr;
    if (m < 256) src = C + m * 300;
    else if (m < 556) src = A + (m - 256) * 300;
    if (src) {
        if (k + 0 < 300) f0 = src[k + 0];
        if (k + 1 < 300) f1 = src[k + 1];
        if (k + 2 < 300) f2 = src[k + 2];
        if (k + 3 < 300) f3 = src[k + 3];
    }
    M[idx] = pack4_fp8(f0, f1, f2, f3);
}

// ---- K1: persistent block (1/CU). 512 thr / 8 waves; wave g owns m-rows [80g,80g+80)
//      (5 mt) x 4 n-tiles; acc = 5x4 = 80. M register-resident: 50 fp8 frags = 100 VGPR.
//      K-loop has ZERO VMEM: 4 ds_read_b64 + 20 MFMA per ks.
//      LDS: single fp8 X-tile, 64 rows x 328 B. NBP bp's sequential.
__global__ __launch_bounds__(512, 2) void gemm_main(
    const float* __restrict__ X, const float* __restrict__ x0,
    const char* __restrict__ M, float* __restrict__ out)
{
    __shared__ char ldsb[64 * LROW];               // 20992 B
    const int tid = threadIdx.x;
    const int wave = tid >> 6, lane = tid & 63;
    const int lr = lane & 15, lg = lane >> 4;
    const int g = wave;
    const int bp0 = blockIdx.x * NBP;

    // staging coords: item i = tid + u*512 -> (t = i%50, jq = i/50), j = jq*4
    int offg[8], offl[8];
    #pragma unroll
    for (int u = 0; u < 8; u++) {
        int i = tid + u * 512;
        int t = i % 50, jq = i / 50;
        offg[u] = jq * 200 + t;                    // float idx into X_bp
        offl[u] = (t + 1) * LROW + jq * 4;         // byte idx into LDS
    }
    const bool v7 = tid < 166;                     // 3750 - 7*512

    // zero-fill LDS once (pad cols 300..327 and rows 51..63 stay zero across bp's)
    #pragma unroll
    for (int u = 0; u < 6; u++) {
        int i = tid + u * 512;
        if (i < 2624) ((ull*)ldsb)[i] = 0ULL;      // 64*328/8
    }

    // ---- register-resident M: wave g -> frags (mt = g*5+j, ks), 8B/lane each ----
    long long mf[5][10];
    #pragma unroll
    for (int j = 0; j < 5; j++)
        #pragma unroll
        for (int ks = 0; ks < 10; ks++)
            mf[j][ks] = *(const long long*)(M + (((g * 5 + j) * 10 + ks) * 64 + lane) * 8);

    __syncthreads();

    for (int it = 0; it < NBP; ++it) {
        const int bp = bp0 + it;
        const int b = bp >> 6, p = bp & 63;
        const float* Xbp = X + bp * 15000;

        // ---- stage [x0 | X_bp] -> fp8 LDS tile ----
        if (tid < 75) {
            f32x4 v = *(const f32x4*)(x0 + bp * 300 + tid * 4);
            *(unsigned*)(ldsb + tid * 4) = pack4_fp8(v.x, v.y, v.z, v.w);   // row 0
        }
        #pragma unroll
        for (int u = 0; u < 8; u++) if (u < 7 || v7) {
            const float* s = Xbp + offg[u];
            *(unsigned*)(ldsb + offl[u]) = pack4_fp8(s[0], s[50], s[100], s[150]);
        }
        __syncthreads();

        // ---- compute: A-frag row = nt*16 + lr, k-bytes ks*32 + lg*8 ----
        f32x4 acc[5][4];
        #pragma unroll
        for (int j = 0; j < 5; j++)
            #pragma unroll
            for (int nt = 0; nt < 4; nt++)
                acc[j][nt] = (f32x4){0.f, 0.f, 0.f, 0.f};

        #pragma unroll
        for (int ks = 0; ks < 10; ks++) {
            long long a0 = *(const long long*)(ldsb + (0 * 16 + lr) * LROW + ks * 32 + lg * 8);
            long long a1 = *(const long long*)(ldsb + (1 * 16 + lr) * LROW + ks * 32 + lg * 8);
            long long a2 = *(const long long*)(ldsb + (2 * 16 + lr) * LROW + ks * 32 + lg * 8);
            long long a3 = *(const long long*)(ldsb + (3 * 16 + lr) * LROW + ks * 32 + lg * 8);
            #pragma unroll
            for (int j = 0; j < 5; j++) {
                acc[j][0] = __builtin_amdgcn_mfma_f32_16x16x32_fp8_fp8(a0, mf[j][ks], acc[j][0], 0, 0, 0);
                acc[j][1] = __builtin_amdgcn_mfma_f32_16x16x32_fp8_fp8(a1, mf[j][ks], acc[j][1], 0, 0, 0);
                acc[j][2] = __builtin_amdgcn_mfma_f32_16x16x32_fp8_fp8(a2, mf[j][ks], acc[j][2], 0, 0, 0);
                acc[j][3] = __builtin_amdgcn_mfma_f32_16x16x32_fp8_fp8(a3, mf[j][ks], acc[j][3], 0, 0, 0);
            }
        }

        // ---- epilogue: col m = g*80 + j*16 + lr, ext-col n = nt*16 + lg*4 + q ----
        {
            const int gr = p >> 3, gc = p & 7;
            #pragma unroll
            for (int j = 0; j < 5; j++) {
                int colm = g * 80 + j * 16 + lr;
                if (colm < 256) {
                    // recon row d -> vid[b][gr*16 + d/16][gc*16 + d%16][t], t = n-1
                    int base = b * 819200 + ((gr * 16 + (colm >> 4)) * 128 + gc * 16 + (colm & 15)) * 50;
                    #pragma unroll
                    for (int nt = 0; nt < 4; nt++) {
                        int t0 = nt * 16 + lg * 4;
                        if (t0 == 0) {
                            out[base + 0] = acc[j][0][1];
                            out[base + 1] = acc[j][0][2];
                            out[base + 2] = acc[j][0][3];
                        } else if (t0 <= 46) {
                            f32x4 v = acc[j][nt];
                            __builtin_memcpy(&out[base + t0 - 1], &v, 16);
                        } else if (t0 == 48) {
                            out[base + 47] = acc[j][nt][0];
                            out[base + 48] = acc[j][nt][1];
                            out[base + 49] = acc[j][nt][2];
                        }
                    }
                } else if (colm < 556) {
                    // X_pred row i = colm-256, t = n
                    int base = OFF_PRED + (bp * 300 + (colm - 256)) * 50;
                    #pragma unroll
                    for (int nt = 0; nt < 4; nt++) {
                        int t0 = nt * 16 + lg * 4;
                        if (t0 <= 46) {
                            f32x4 v = acc[j][nt];
                            __builtin_memcpy(&out[base + t0], &v, 16);
                        } else if (t0 == 48) {
                            out[base + 48] = acc[j][nt][0];
                            out[base + 49] = acc[j][nt][1];
                        }
                    }
                }
            }
        }
        __syncthreads();   // protect LDS before next bp's staging
    }
}

// ---- K2: X_U[b,i,t] = 0.5*(1+exp(-(B·U)[b,i,t])) * sum_p |X[b,p,i,t]|
__global__ void xu_kernel(const float* __restrict__ X, const float* __restrict__ U,
                          const float* __restrict__ B, float* __restrict__ out) {
    int id = blockIdx.x * 256 + threadIdx.x;
    if (id >= 480000) return;
    int t = id % 50;
    int i = (id / 50) % 300;
    int b = id / 15000;
    const float* xp = X + b * 960000 + i * 50 + t;
    float s = 0.f;
    #pragma unroll 8
    for (int pp = 0; pp < 64; pp++) s += fabsf(xp[pp * 15000]);
    float bu = 0.f;
    const float* up = U + b * 2000 + t;
    const float* Bp = B + i * 40;
    #pragma unroll 8
    for (int q = 0; q < 40; q++) bu += Bp[q] * up[q * 50];
    out[OFF_XU + id] = 0.5f * (1.f + expf(-bu)) * s;
}

extern "C" void kernel_launch(void* const* d_in, const int* in_sizes, int n_in,
                              void* d_out, int out_size, void* d_ws, size_t ws_size,
                              hipStream_t stream) {
    const float* X  = (const float*)d_in[0];
    const float* U  = (const float*)d_in[1];
    const float* x0 = (const float*)d_in[2];
    const float* A  = (const float*)d_in[3];
    const float* B  = (const float*)d_in[4];
    const float* C  = (const float*)d_in[5];
    float* out = (float*)d_out;
    unsigned* M = (unsigned*)d_ws;      // 640*320 fp8 = 204,800 B (fragment-ordered)

    build_M<<<200, 256, 0, stream>>>(A, C, M);
    gemm_main<<<256, 512, 0, stream>>>(X, x0, (const char*)M, out);
    xu_kernel<<<1875, 256, 0, stream>>>(X, U, B, out);
}